// Round 2
// baseline (527.634 us; speedup 1.0000x reference)
//
#include <hip/hip_runtime.h>

// SpectralClassifier: the DCT-II -> bandpass(k in [0,15)) -> IDCT -> mean(m)
// chain collapses analytically: sum_m IDCT-basis(m,k) == 0 for all k>=1
// (sum_{m=0}^{N-1} cos((2m+1)pi k/2N) = sin(pi k)/(2 sin(pi k/2N)) = 0), so
// only the k=0 (DC) term survives:
//   v[b,d] = (1/127) * sum_{s=1..127} mask[b,s] * hidden[b,s,d]
// followed by the 768->256->64->2 ReLU MLP.
//
// NOTE on dur_us: harness reset traffic (1.5 GiB 0xAA poison fill ~248 us +
// 402 MB hidden restore ~125 us) dominates the reported duration; the two
// kernels below are a ~40-55 us slice. Optimizations target that slice.
//
// R2 changes (post-mortem of R1's failed uniform-global experiment):
//  - R1 bet the compiler would scalarize block-uniform global loads to
//    s_load; it does not (v is writable memory), so layer 1 became per-lane
//    same-address global_load_dwordx4 -- same 1KB/instr writeback as the LDS
//    broadcast, slightly worse (+5us, matching the VMEM-vs-LDS instr cost).
//  - Real lever: broadcast cost is per-WAVE-INSTRUCTION. Remap layer 1 so
//    wave w owns row w and each lane owns 4 contiguous output columns:
//    ds_read_b128 per wave drops 4x (768 -> 192, own row only) and the four
//    scalar W1 loads per k fuse into one coalesced global_load_dwordx4.
//    Layer-1 cost: ~15us (LDS-pipe-bound) -> ~6us (W1 L2-stream-bound).
//  - Kernel 1 unchanged (HBM-bound at its ~201 MB floor).

#define BB   1024
#define SS   128
#define DD   768
#define VEC4 (DD / 4)   // 192 float4 per row

// native clang vector type: required by __builtin_nontemporal_load
// (HIP's float4 is a struct and is rejected by the builtin)
typedef float floatx4 __attribute__((ext_vector_type(4)));

// ---------------- Kernel 1: masked row-sum over seq (HBM-bound) ------------
// One block per batch, 192 threads = one float4 column each. Active seq
// positions are compacted (as precomputed float4 offsets) into LDS so the
// inner loop is branch-free and masked-out rows are never fetched
// (~201 MB instead of 402 MB for the ~50%-dense mask).
//
// Mask dtype: bool is marshaled as int32 by the harness; a cheap PARALLEL
// probe (128 threads, one putative int32 element each) keeps us robust to
// uint8 marshaling without serial-loop latency.
__global__ __launch_bounds__(192) void spectral_reduce_kernel(
    const float* __restrict__ hidden,        // [B,S,D]
    const unsigned char* __restrict__ mask8, // [B,S] bool: int32 or uint8
    float* __restrict__ v)                   // [B,D]
{
    const int b = blockIdx.x;
    const int t = threadIdx.x;  // 0..191

    __shared__ int slist[SS];
    __shared__ int wcnt[2];
    __shared__ int not_i32;
    if (t == 0) not_i32 = 0;
    __syncthreads();

    if (t < 128) {
        // bytes 1..3 of putative int32 element t: nonzero => not int32 {0,1}
        const unsigned char* p = mask8 + 4 * t;
        if (p[1] | p[2] | p[3]) not_i32 = 1;   // benign race, same value
    }
    __syncthreads();

    const int as_i32 = !not_i32;

    // ballot-based compaction of active positions 1..127 (CLS at s=0 dropped).
    // Waves 0 and 1 cover s=0..127; wave 2 (t>=128) contributes mv=0.
    const int lane = t & 63;
    const int w    = t >> 6;
    int mv = 0;
    if (t >= 1 && t < 128) {
        size_t idx = (size_t)b * SS + t;
        mv = as_i32 ? (((const int*)mask8)[idx] != 0) : (mask8[idx] != 0);
    }
    unsigned long long bm = __ballot(mv);
    if (lane == 0 && w < 2) wcnt[w] = (int)__popcll(bm);
    const int rank = (int)__popcll(bm & ((1ull << lane) - 1ull));
    __syncthreads();

    if (mv) slist[(w ? wcnt[0] : 0) + rank] = t * VEC4;  // float4 offset
    const int n = wcnt[0] + wcnt[1];
    __syncthreads();

    const floatx4* hp = (const floatx4*)(hidden + (size_t)b * SS * DD);

    // hidden is streamed exactly once -> nontemporal, keep L2/L3 for weights
    floatx4 a0 = (floatx4)0.f;
    floatx4 a1 = (floatx4)0.f;
    int i = 0;
    for (; i + 7 < n; i += 8) {                // 8 loads in flight per lane
        floatx4 x0 = __builtin_nontemporal_load(&hp[slist[i + 0] + t]);
        floatx4 x1 = __builtin_nontemporal_load(&hp[slist[i + 1] + t]);
        floatx4 x2 = __builtin_nontemporal_load(&hp[slist[i + 2] + t]);
        floatx4 x3 = __builtin_nontemporal_load(&hp[slist[i + 3] + t]);
        floatx4 x4 = __builtin_nontemporal_load(&hp[slist[i + 4] + t]);
        floatx4 x5 = __builtin_nontemporal_load(&hp[slist[i + 5] + t]);
        floatx4 x6 = __builtin_nontemporal_load(&hp[slist[i + 6] + t]);
        floatx4 x7 = __builtin_nontemporal_load(&hp[slist[i + 7] + t]);
        a0 += x0; a1 += x1; a0 += x2; a1 += x3;
        a0 += x4; a1 += x5; a0 += x6; a1 += x7;
    }
    for (; i < n; ++i) {
        a0 += __builtin_nontemporal_load(&hp[slist[i] + t]);
    }
    a0 += a1;

    const float sc = 1.0f / 127.0f;
    floatx4 r = a0 * sc;
    ((floatx4*)(v + (size_t)b * DD))[t] = r;   // cached: kernel 2 re-reads it
}

// ---------------- Kernel 2: fused 3-layer MLP ------------------------------
// BM=4 batch rows per block, 256 threads, 256 blocks (1/CU). W1 (768 KB)
// is read once per block from L2/L3.
// Layer 1 work map: wave w owns batch row w; lane owns output columns
// 4*lane..4*lane+3. Per wave: 192 ds_read_b128 of its OWN row (broadcast)
// and 768 coalesced global_load_dwordx4 of W1. LDS pipe ~9.2K cyc/CU,
// W1 L2 stream ~14K cyc/CU (the floor), FMA ~6.1K cyc/SIMD.
#define BM 4
__global__ __launch_bounds__(256) void spectral_mlp_kernel(
    const float* __restrict__ v,   // [B,D]
    const float* __restrict__ W1, const float* __restrict__ b1,  // [768,256],[256]
    const float* __restrict__ W2, const float* __restrict__ b2,  // [256,64],[64]
    const float* __restrict__ W3, const float* __restrict__ b3,  // [64,2],[2]
    float* __restrict__ out)       // [B,2]
{
    __shared__ float vs[BM * DD];     // 12 KB
    __shared__ float h1[BM][256];     // 4 KB
    __shared__ float h2[BM][64];      // 1 KB

    const int t  = threadIdx.x;
    const int b0 = blockIdx.x * BM;

    // stage v rows, vectorized: 768 float4 over 256 threads (3 each)
    {
        const floatx4* src = (const floatx4*)(v + (size_t)b0 * DD);
        floatx4* dst = (floatx4*)vs;
        #pragma unroll
        for (int i = t; i < BM * VEC4; i += 256)
            dst[i] = src[i];
    }
    __syncthreads();

    // ---- layer 1: wave w -> row w; lane -> cols [4*lane, 4*lane+4) ----
    {
        const int w    = t >> 6;       // 0..3, wave-uniform
        const int lane = t & 63;
        const int c4   = lane * 4;

        floatx4 bias = *(const floatx4*)(b1 + c4);
        float a0 = bias.x, a1 = bias.y, a2 = bias.z, a3 = bias.w;

        const floatx4* vr = (const floatx4*)(vs + w * DD);
        const float*   Wc = W1 + c4;   // column base; row stride 256 floats

        #pragma unroll 4
        for (int i4 = 0; i4 < VEC4; ++i4) {    // 192 groups of 4 k-steps
            floatx4 x  = vr[i4];               // ds_read_b128, own row only
            floatx4 w0 = *(const floatx4*)(Wc + (size_t)(4 * i4 + 0) * 256);
            floatx4 w1 = *(const floatx4*)(Wc + (size_t)(4 * i4 + 1) * 256);
            floatx4 w2 = *(const floatx4*)(Wc + (size_t)(4 * i4 + 2) * 256);
            floatx4 w3 = *(const floatx4*)(Wc + (size_t)(4 * i4 + 3) * 256);
            a0 = fmaf(x.x, w0.x, a0); a1 = fmaf(x.x, w0.y, a1);
            a2 = fmaf(x.x, w0.z, a2); a3 = fmaf(x.x, w0.w, a3);
            a0 = fmaf(x.y, w1.x, a0); a1 = fmaf(x.y, w1.y, a1);
            a2 = fmaf(x.y, w1.z, a2); a3 = fmaf(x.y, w1.w, a3);
            a0 = fmaf(x.z, w2.x, a0); a1 = fmaf(x.z, w2.y, a1);
            a2 = fmaf(x.z, w2.z, a2); a3 = fmaf(x.z, w2.w, a3);
            a0 = fmaf(x.w, w3.x, a0); a1 = fmaf(x.w, w3.y, a1);
            a2 = fmaf(x.w, w3.z, a2); a3 = fmaf(x.w, w3.w, a3);
        }
        floatx4 r;
        r.x = fmaxf(a0, 0.f); r.y = fmaxf(a1, 0.f);
        r.z = fmaxf(a2, 0.f); r.w = fmaxf(a3, 0.f);
        *(floatx4*)&h1[w][c4] = r;             // ds_write_b128
    }
    __syncthreads();

    // ---- layer 2: 4 rows x 64 cols = 256 outputs, one per thread ----
    {
        const int r = t >> 6;      // wave-uniform (64-lane waves)
        const int j = t & 63;
        float a = b2[j];
        const floatx4* hr = (const floatx4*)h1[r];  // 1 KB-aligned
        #pragma unroll 4
        for (int i4 = 0; i4 < 64; ++i4) {
            floatx4 x = hr[i4];                 // ds_read_b128, broadcast
            a = fmaf(x.x, W2[(4 * i4 + 0) * 64 + j], a);
            a = fmaf(x.y, W2[(4 * i4 + 1) * 64 + j], a);
            a = fmaf(x.z, W2[(4 * i4 + 2) * 64 + j], a);
            a = fmaf(x.w, W2[(4 * i4 + 3) * 64 + j], a);
        }
        h2[r][j] = fmaxf(a, 0.f);
    }
    __syncthreads();

    // ---- layer 3: 4 rows x 2 logits ----
    if (t < BM * 2) {
        const int r = t >> 1;
        const int c = t & 1;
        float a = b3[c];
        const floatx4* hr = (const floatx4*)h2[r];
        #pragma unroll
        for (int i4 = 0; i4 < 16; ++i4) {
            floatx4 x = hr[i4];
            a = fmaf(x.x, W3[(4 * i4 + 0) * 2 + c], a);
            a = fmaf(x.y, W3[(4 * i4 + 1) * 2 + c], a);
            a = fmaf(x.z, W3[(4 * i4 + 2) * 2 + c], a);
            a = fmaf(x.w, W3[(4 * i4 + 3) * 2 + c], a);
        }
        out[(size_t)(b0 + r) * 2 + c] = a;
    }
}

extern "C" void kernel_launch(void* const* d_in, const int* in_sizes, int n_in,
                              void* d_out, int out_size, void* d_ws, size_t ws_size,
                              hipStream_t stream) {
    const float*         hidden = (const float*)d_in[0];
    const unsigned char* mask   = (const unsigned char*)d_in[1];  // dtype probed in-kernel
    const float*         W1     = (const float*)d_in[2];
    const float*         b1     = (const float*)d_in[3];
    const float*         W2     = (const float*)d_in[4];
    const float*         b2     = (const float*)d_in[5];
    const float*         W3     = (const float*)d_in[6];
    const float*         b3     = (const float*)d_in[7];
    float*               out    = (float*)d_out;

    float* v = (float*)d_ws;  // [B, D] = 3 MB scratch

    spectral_reduce_kernel<<<BB, 192, 0, stream>>>(hidden, mask, v);
    spectral_mlp_kernel<<<BB / BM, 256, 0, stream>>>(v, W1, b1, W2, b2, W3, b3, out);
}

// Round 3
// 504.109 us; speedup vs baseline: 1.0467x; 1.0467x over previous
//
#include <hip/hip_runtime.h>

// SpectralClassifier: the DCT-II -> bandpass(k in [0,15)) -> IDCT -> mean(m)
// chain collapses analytically: sum_m IDCT-basis(m,k) == 0 for all k>=1
// (sum_{m=0}^{N-1} cos((2m+1)pi k/2N) = sin(pi k)/(2 sin(pi k/2N)) = 0), so
// only the k=0 (DC) term survives:
//   v[b,d] = (1/127) * sum_{s=1..127} mask[b,s] * hidden[b,s,d]
// followed by the 768->256->64->2 ReLU MLP.
//
// NOTE on dur_us: harness reset traffic (1.5 GiB 0xAA poison fill ~248 us +
// hidden restore) dominates the reported duration; the kernels below are a
// ~40-55 us slice. Optimizations target that slice.
//
// Cost model pinned down by R1/R2 failures:
//  - LDS broadcast ds_read_b128 ~12 cyc PER WAVE-INSTR on the shared pipe.
//  - W1 must be read exactly once per block: R2's wave-owns-row map made
//    every wave read all of W1 (4x L2 traffic, +15.6 us observed ~= +17
//    modeled). R1's same-address VMEM broadcast is no cheaper than LDS.
// R3: waves partition K instead of columns. Wave w owns k in [192w,192w+192);
// lane owns a 4-row x 4-col register tile. Per wave: 192 ds_read_b128
// (4x fewer than baseline), 192 coalesced global_load_dwordx4 of W1 (1x
// coverage), 3072 FMA. LDS reduction combines the 4 k-partials.
// Layer 1: ~15.4 us (LDS-pipe-bound) -> ~6 us (W1 L2-stream-bound).

#define BB   1024
#define SS   128
#define DD   768
#define VEC4 (DD / 4)   // 192 float4 per row

// native clang vector type: required by __builtin_nontemporal_load
// (HIP's float4 is a struct and is rejected by the builtin)
typedef float floatx4 __attribute__((ext_vector_type(4)));

// ---------------- Kernel 1: masked row-sum over seq (HBM-bound) ------------
// One block per batch, 192 threads = one float4 column each. Active seq
// positions are compacted (as precomputed float4 offsets) into LDS so the
// inner loop is branch-free and masked-out rows are never fetched
// (~201 MB instead of 402 MB for the ~50%-dense mask).
//
// Mask dtype: bool is marshaled as int32 by the harness; a cheap PARALLEL
// probe (128 threads, one putative int32 element each) keeps us robust to
// uint8 marshaling without serial-loop latency.
__global__ __launch_bounds__(192) void spectral_reduce_kernel(
    const float* __restrict__ hidden,        // [B,S,D]
    const unsigned char* __restrict__ mask8, // [B,S] bool: int32 or uint8
    float* __restrict__ v)                   // [B,D]
{
    const int b = blockIdx.x;
    const int t = threadIdx.x;  // 0..191

    __shared__ int slist[SS];
    __shared__ int wcnt[2];
    __shared__ int not_i32;
    if (t == 0) not_i32 = 0;
    __syncthreads();

    if (t < 128) {
        // bytes 1..3 of putative int32 element t: nonzero => not int32 {0,1}
        const unsigned char* p = mask8 + 4 * t;
        if (p[1] | p[2] | p[3]) not_i32 = 1;   // benign race, same value
    }
    __syncthreads();

    const int as_i32 = !not_i32;

    // ballot-based compaction of active positions 1..127 (CLS at s=0 dropped).
    // Waves 0 and 1 cover s=0..127; wave 2 (t>=128) contributes mv=0.
    const int lane = t & 63;
    const int w    = t >> 6;
    int mv = 0;
    if (t >= 1 && t < 128) {
        size_t idx = (size_t)b * SS + t;
        mv = as_i32 ? (((const int*)mask8)[idx] != 0) : (mask8[idx] != 0);
    }
    unsigned long long bm = __ballot(mv);
    if (lane == 0 && w < 2) wcnt[w] = (int)__popcll(bm);
    const int rank = (int)__popcll(bm & ((1ull << lane) - 1ull));
    __syncthreads();

    if (mv) slist[(w ? wcnt[0] : 0) + rank] = t * VEC4;  // float4 offset
    const int n = wcnt[0] + wcnt[1];
    __syncthreads();

    const floatx4* hp = (const floatx4*)(hidden + (size_t)b * SS * DD);

    // hidden is streamed exactly once -> nontemporal, keep L2/L3 for weights
    floatx4 a0 = (floatx4)0.f;
    floatx4 a1 = (floatx4)0.f;
    int i = 0;
    for (; i + 7 < n; i += 8) {                // 8 loads in flight per lane
        floatx4 x0 = __builtin_nontemporal_load(&hp[slist[i + 0] + t]);
        floatx4 x1 = __builtin_nontemporal_load(&hp[slist[i + 1] + t]);
        floatx4 x2 = __builtin_nontemporal_load(&hp[slist[i + 2] + t]);
        floatx4 x3 = __builtin_nontemporal_load(&hp[slist[i + 3] + t]);
        floatx4 x4 = __builtin_nontemporal_load(&hp[slist[i + 4] + t]);
        floatx4 x5 = __builtin_nontemporal_load(&hp[slist[i + 5] + t]);
        floatx4 x6 = __builtin_nontemporal_load(&hp[slist[i + 6] + t]);
        floatx4 x7 = __builtin_nontemporal_load(&hp[slist[i + 7] + t]);
        a0 += x0; a1 += x1; a0 += x2; a1 += x3;
        a0 += x4; a1 += x5; a0 += x6; a1 += x7;
    }
    for (; i < n; ++i) {
        a0 += __builtin_nontemporal_load(&hp[slist[i] + t]);
    }
    a0 += a1;

    const float sc = 1.0f / 127.0f;
    floatx4 r = a0 * sc;
    ((floatx4*)(v + (size_t)b * DD))[t] = r;   // cached: kernel 2 re-reads it
}

// ---------------- Kernel 2: fused 3-layer MLP ------------------------------
// BM=4 batch rows per block, 256 threads, 256 blocks (1/CU). W1 (768 KB)
// is read once per block from L2/L3 (197 MB aggregate ~ 5.7 us, the floor).
// Layer 1: waves partition K (wave w: k in [192w, 192w+192)); each lane owns
// a 4-row x 4-col register tile (cols 4*lane..4*lane+3). Per wave: 192
// broadcast ds_read_b128 of vs + 192 coalesced dwordx4 of W1 (exactly-once
// coverage) + 3072 FMA. 16 KB LDS partial buffer + tree-reduce over the 4
// waves, then bias+ReLU.
#define BM 4
__global__ __launch_bounds__(256) void spectral_mlp_kernel(
    const float* __restrict__ v,   // [B,D]
    const float* __restrict__ W1, const float* __restrict__ b1,  // [768,256],[256]
    const float* __restrict__ W2, const float* __restrict__ b2,  // [256,64],[64]
    const float* __restrict__ W3, const float* __restrict__ b3,  // [64,2],[2]
    float* __restrict__ out)       // [B,2]
{
    __shared__ float vs[BM * DD];        // 12 KB
    __shared__ float hpart[4][BM][256];  // 16 KB layer-1 k-partials
    __shared__ float h1[BM][256];        // 4 KB
    __shared__ float h2[BM][64];         // 1 KB

    const int t    = threadIdx.x;
    const int b0   = blockIdx.x * BM;
    const int w    = t >> 6;        // wave 0..3 (wave-uniform)
    const int lane = t & 63;
    const int c4   = lane * 4;      // this lane's 4 output columns

    // stage v rows, vectorized: 768 float4 over 256 threads (3 each)
    {
        const floatx4* src = (const floatx4*)(v + (size_t)b0 * DD);
        floatx4* dst = (floatx4*)vs;
        #pragma unroll
        for (int i = t; i < BM * VEC4; i += 256)
            dst[i] = src[i];
    }
    __syncthreads();

    // ---- layer 1 partials: wave w covers i4 in [48w, 48w+48) ----
    {
        float acc[4][4] = {};  // [row][col], all compile-time indexed
        const floatx4* vr0 = (const floatx4*)vs;
        const floatx4* vr1 = (const floatx4*)(vs + DD);
        const floatx4* vr2 = (const floatx4*)(vs + 2 * DD);
        const floatx4* vr3 = (const floatx4*)(vs + 3 * DD);
        const float*   Wc  = W1 + c4;   // column base; row stride 256 floats

        const int i4beg = 48 * w;
        #pragma unroll 4
        for (int i4 = i4beg; i4 < i4beg + 48; ++i4) {
            floatx4 x0 = vr0[i4];              // broadcast ds_read_b128
            floatx4 x1 = vr1[i4];
            floatx4 x2 = vr2[i4];
            floatx4 x3 = vr3[i4];
            floatx4 wv[4];
            #pragma unroll
            for (int j = 0; j < 4; ++j)        // coalesced 1 KB/wave-instr
                wv[j] = *(const floatx4*)(Wc + (size_t)(4 * i4 + j) * 256);
            #pragma unroll
            for (int j = 0; j < 4; ++j) {
                #pragma unroll
                for (int c = 0; c < 4; ++c) {
                    acc[0][c] = fmaf(x0[j], wv[j][c], acc[0][c]);
                    acc[1][c] = fmaf(x1[j], wv[j][c], acc[1][c]);
                    acc[2][c] = fmaf(x2[j], wv[j][c], acc[2][c]);
                    acc[3][c] = fmaf(x3[j], wv[j][c], acc[3][c]);
                }
            }
        }
        #pragma unroll
        for (int r = 0; r < 4; ++r) {
            floatx4 p;
            p[0] = acc[r][0]; p[1] = acc[r][1];
            p[2] = acc[r][2]; p[3] = acc[r][3];
            *(floatx4*)&hpart[w][r][c4] = p;   // contiguous 1 KB/wave-instr
        }
    }
    __syncthreads();

    // ---- reduce the 4 k-partials, add bias, ReLU ----
    {
        const int r = w;                        // wave w finishes row w
        floatx4 s0 = *(const floatx4*)&hpart[0][r][c4];
        floatx4 s1 = *(const floatx4*)&hpart[1][r][c4];
        floatx4 s2 = *(const floatx4*)&hpart[2][r][c4];
        floatx4 s3 = *(const floatx4*)&hpart[3][r][c4];
        floatx4 bias = *(const floatx4*)(b1 + c4);
        floatx4 s = (s0 + s1) + (s2 + s3) + bias;
        floatx4 rl;
        rl[0] = fmaxf(s[0], 0.f); rl[1] = fmaxf(s[1], 0.f);
        rl[2] = fmaxf(s[2], 0.f); rl[3] = fmaxf(s[3], 0.f);
        *(floatx4*)&h1[r][c4] = rl;
    }
    __syncthreads();

    // ---- layer 2: 4 rows x 64 cols = 256 outputs, one per thread ----
    {
        const int r = t >> 6;      // wave-uniform (64-lane waves)
        const int j = t & 63;
        float a = b2[j];
        const floatx4* hr = (const floatx4*)h1[r];  // 1 KB-aligned
        #pragma unroll 4
        for (int i4 = 0; i4 < 64; ++i4) {
            floatx4 x = hr[i4];                 // ds_read_b128, broadcast
            a = fmaf(x.x, W2[(4 * i4 + 0) * 64 + j], a);
            a = fmaf(x.y, W2[(4 * i4 + 1) * 64 + j], a);
            a = fmaf(x.z, W2[(4 * i4 + 2) * 64 + j], a);
            a = fmaf(x.w, W2[(4 * i4 + 3) * 64 + j], a);
        }
        h2[r][j] = fmaxf(a, 0.f);
    }
    __syncthreads();

    // ---- layer 3: 4 rows x 2 logits ----
    if (t < BM * 2) {
        const int r = t >> 1;
        const int c = t & 1;
        float a = b3[c];
        const floatx4* hr = (const floatx4*)h2[r];
        #pragma unroll
        for (int i4 = 0; i4 < 16; ++i4) {
            floatx4 x = hr[i4];
            a = fmaf(x.x, W3[(4 * i4 + 0) * 2 + c], a);
            a = fmaf(x.y, W3[(4 * i4 + 1) * 2 + c], a);
            a = fmaf(x.z, W3[(4 * i4 + 2) * 2 + c], a);
            a = fmaf(x.w, W3[(4 * i4 + 3) * 2 + c], a);
        }
        out[(size_t)(b0 + r) * 2 + c] = a;
    }
}

extern "C" void kernel_launch(void* const* d_in, const int* in_sizes, int n_in,
                              void* d_out, int out_size, void* d_ws, size_t ws_size,
                              hipStream_t stream) {
    const float*         hidden = (const float*)d_in[0];
    const unsigned char* mask   = (const unsigned char*)d_in[1];  // dtype probed in-kernel
    const float*         W1     = (const float*)d_in[2];
    const float*         b1     = (const float*)d_in[3];
    const float*         W2     = (const float*)d_in[4];
    const float*         b2     = (const float*)d_in[5];
    const float*         W3     = (const float*)d_in[6];
    const float*         b3     = (const float*)d_in[7];
    float*               out    = (float*)d_out;

    float* v = (float*)d_ws;  // [B, D] = 3 MB scratch

    spectral_reduce_kernel<<<BB, 192, 0, stream>>>(hidden, mask, v);
    spectral_mlp_kernel<<<BB / BM, 256, 0, stream>>>(v, W1, b1, W2, b2, W3, b3, out);
}